// Round 3
// baseline (1344.490 us; speedup 1.0000x reference)
//
#include <hip/hip_runtime.h>

// Swin-V2 shifted-window attention, MI355X (gfx950), runtime dtype dispatch.
// sniff: detect input dtype (fp32 vs bf16) from Wq bit patterns -> flag in d_ws.
// cpb:   CPB-MLP bias table [225][8] fp32 -> d_ws.
// swin_fused<F32>: one block per window (4 waves, 2 head-passes): QKV proj (MFMA),
//   cosine attention + CPB bias + shift mask + softmax, PV, Wo proj, unshift scatter.
//   Both instantiations launch; the wrong one exits on the flag (uniform).
// MFMA 16x16x32 bf16 layouts (HW-verified): A[m=lane&15][k=(lane>>4)*8+j],
// C/D[col=lane&15][row=(lane>>4)*4+reg]; B mirrors A.

typedef __bf16 bf16_t;
typedef __attribute__((ext_vector_type(8))) __bf16 bf16x8;
typedef __attribute__((ext_vector_type(4))) float f32x4;

__device__ __forceinline__ f32x4 mfma16(bf16x8 a, bf16x8 b, f32x4 c) {
  return __builtin_amdgcn_mfma_f32_16x16x32_bf16(a, b, c, 0, 0, 0);
}

// scalar load, dtype-dispatched
__device__ __forceinline__ float ldf(const void* p, int i, bool f32) {
  return f32 ? ((const float*)p)[i] : (float)((const bf16_t*)p)[i];
}
// 8-element load -> bf16x8, dtype-dispatched (i multiple of 8)
__device__ __forceinline__ bf16x8 ld8(const void* p, int i, bool f32) {
  if (f32) {
    const float* f = (const float*)p + i;
    float4 a = *(const float4*)f;
    float4 b = *(const float4*)(f + 4);
    bf16x8 r;
    r[0] = (bf16_t)a.x; r[1] = (bf16_t)a.y; r[2] = (bf16_t)a.z; r[3] = (bf16_t)a.w;
    r[4] = (bf16_t)b.x; r[5] = (bf16_t)b.y; r[6] = (bf16_t)b.z; r[7] = (bf16_t)b.w;
    return r;
  }
  return *(const bf16x8*)((const bf16_t*)p + i);
}

__device__ __forceinline__ float clampv(float v) {
  return fminf(fmaxf(v, -1.0e4f), 1.0e4f);  // IEEE min/max: also converts NaN -> -1e4
}

// ---------------- sniff: fp32 vs bf16 detection on Wq ----------------
__global__ void sniff_kernel(const unsigned int* __restrict__ w, int* __restrict__ flag) {
  int t = threadIdx.x;  // one wave (64)
  int cnt = 0;
#pragma unroll
  for (int i = 0; i < 4; ++i) {
    unsigned int v = w[t * 4 + i];
    unsigned int elo = (v >> 7) & 0xFF;          // exponent of low 16 bits as bf16
    if (elo >= 0x70 && elo <= 0x7F) cnt++;       // plausible magnitude [2^-15, 2)
  }
  cnt += __shfl_xor(cnt, 1);  cnt += __shfl_xor(cnt, 2);  cnt += __shfl_xor(cnt, 4);
  cnt += __shfl_xor(cnt, 8);  cnt += __shfl_xor(cnt, 16); cnt += __shfl_xor(cnt, 32);
  if (t == 0) *flag = (cnt >= 128) ? 0 : 1;      // 0 = bf16 inputs, 1 = fp32 inputs
}

// ---------------- CPB-MLP bias table -> d_ws ----------------
__global__ void cpb_kernel(const void* __restrict__ w1, const void* __restrict__ b1,
                           const void* __restrict__ w2, float* __restrict__ tab,
                           const int* __restrict__ flagp) {
  const bool f32 = (*flagp != 0);
  int e = threadIdx.x;
  if (e >= 225) return;
  int a = e / 15, bcol = e % 15;
  float t0 = ((float)(a - 7) / 7.0f) * 8.0f;
  float t1 = ((float)(bcol - 7) / 7.0f) * 8.0f;
  float s0 = (t0 > 0.f) ? 1.f : ((t0 < 0.f) ? -1.f : 0.f);
  float s1 = (t1 > 0.f) ? 1.f : ((t1 < 0.f) ? -1.f : 0.f);
  t0 = s0 * log2f(fabsf(t0) + 1.f) * (1.0f / 3.0f);  // /log2(8)
  t1 = s1 * log2f(fabsf(t1) + 1.f) * (1.0f / 3.0f);
  float accv[8];
#pragma unroll
  for (int i = 0; i < 8; ++i) accv[i] = 0.f;
  for (int j = 0; j < 512; ++j) {
    float hd = t0 * ldf(w1, 2 * j, f32) + t1 * ldf(w1, 2 * j + 1, f32) + ldf(b1, j, f32);
    hd = fmaxf(hd, 0.f);
#pragma unroll
    for (int hh = 0; hh < 8; ++hh) accv[hh] += hd * ldf(w2, hh * 512 + j, f32);
  }
#pragma unroll
  for (int hh = 0; hh < 8; ++hh)
    tab[e * 8 + hh] = 16.f / (1.f + __expf(-accv[hh]));
}

// ---------------- fused per-window attention ----------------
template <bool F32>
__global__ void __launch_bounds__(256) swin_fused(
    const void* __restrict__ x,
    const void* __restrict__ Wq, const void* __restrict__ bq,
    const void* __restrict__ Wk, const void* __restrict__ bk,
    const void* __restrict__ Wv, const void* __restrict__ bv,
    const void* __restrict__ Wo, const void* __restrict__ bo,
    const void* __restrict__ ls,
    const float* __restrict__ btab,
    const int* __restrict__ flagp,
    void* __restrict__ outv) {
  if ((*flagp != 0) != F32) return;  // uniform across grid; exits before any barrier

  __shared__ __align__(16) bf16_t sm[4 * 6144];   // 48 KB: per-wave qn|kn|vT scratch
  __shared__ __align__(16) bf16_t ybuf[64 * 256]; // 32 KB: attention output, all heads
  const int lane = threadIdx.x & 63;
  const int wave = threadIdx.x >> 6;
  const int quad = lane >> 4;
  const int l16  = lane & 15;
  const int win  = blockIdx.x;
  const int bb   = win >> 6;
  const int wh   = (win >> 3) & 7;
  const int ww   = win & 7;
  const int ko   = quad * 8;

  bf16_t* lq  = sm + wave * 6144;
  bf16_t* lk  = lq + 2048;
  bf16_t* lvT = lq + 4096;
  const f32x4 fzero = {0.f, 0.f, 0.f, 0.f};

  // token -> x element offsets (cyclic shift +4, window gather)
  int aoff[4];
#pragma unroll
  for (int mi = 0; mi < 4; ++mi) {
    int t  = mi * 16 + l16;
    int gh = (wh * 8 + (t >> 3) + 4) & 63;
    int gw = (ww * 8 + (t & 7) + 4) & 63;
    aoff[mi] = ((bb * 64 + gh) * 64 + gw) * 256;
  }

  // key-region ids for shifted-window mask
  int regm[4];
#pragma unroll
  for (int ni = 0; ni < 4; ++ni) {
    int m  = ni * 16 + l16;
    int rr = (wh == 7) ? (((m >> 3) < 4) ? 1 : 2) : 0;
    int cc = (ww == 7) ? (((m & 7) < 4) ? 1 : 2) : 0;
    regm[ni] = rr * 3 + cc;
  }

  for (int hp = 0; hp < 2; ++hp) {
    const int h = hp * 4 + wave;

    // ---- Phase A: QKV projection for head h ----
    int boff[6];
    boff[0] = (h * 32 + l16) * 256;        // Wq row block 0
    boff[1] = (h * 32 + 16 + l16) * 256;   // Wq row block 1
    boff[2] = boff[0];                     // Wk
    boff[3] = boff[1];
    boff[4] = boff[0];                     // Wv
    boff[5] = boff[1];

    f32x4 acc[4][6];
#pragma unroll
    for (int mi = 0; mi < 4; ++mi)
#pragma unroll
      for (int ni = 0; ni < 6; ++ni) acc[mi][ni] = fzero;

#pragma unroll
    for (int kk = 0; kk < 8; ++kk) {
      const int kof = kk * 32 + ko;
      bf16x8 af[4];
#pragma unroll
      for (int mi = 0; mi < 4; ++mi) af[mi] = ld8(x, aoff[mi] + kof, F32);
      const void* wptr[3] = {Wq, Wk, Wv};
#pragma unroll
      for (int ni = 0; ni < 6; ++ni) {
        bf16x8 bfr = ld8(wptr[ni >> 1], boff[ni] + kof, F32);
#pragma unroll
        for (int mi = 0; mi < 4; ++mi) acc[mi][ni] = mfma16(af[mi], bfr, acc[mi][ni]);
      }
    }

    const float bias_q0 = ldf(bq, h * 32 + l16, F32);
    const float bias_q1 = ldf(bq, h * 32 + 16 + l16, F32);
    const float bias_k0 = ldf(bk, h * 32 + l16, F32);
    const float bias_k1 = ldf(bk, h * 32 + 16 + l16, F32);
    const float bias_v0 = ldf(bv, h * 32 + l16, F32);
    const float bias_v1 = ldf(bv, h * 32 + 16 + l16, F32);

    // ---- Phase B: bias + cosine-normalize; stage qn,kn,vT to LDS ----
#pragma unroll
    for (int mi = 0; mi < 4; ++mi)
#pragma unroll
      for (int r = 0; r < 4; ++r) {
        float q0 = acc[mi][0][r] + bias_q0, q1 = acc[mi][1][r] + bias_q1;
        float k0 = acc[mi][2][r] + bias_k0, k1 = acc[mi][3][r] + bias_k1;
        float sq = q0 * q0 + q1 * q1;
        sq += __shfl_xor(sq, 1); sq += __shfl_xor(sq, 2);
        sq += __shfl_xor(sq, 4); sq += __shfl_xor(sq, 8);
        float rq = 1.f / fmaxf(sqrtf(sq), 1e-12f);
        float sk = k0 * k0 + k1 * k1;
        sk += __shfl_xor(sk, 1); sk += __shfl_xor(sk, 2);
        sk += __shfl_xor(sk, 4); sk += __shfl_xor(sk, 8);
        float rk = 1.f / fmaxf(sqrtf(sk), 1e-12f);
        int row = mi * 16 + quad * 4 + r;
        lq[row * 32 + l16]      = (bf16_t)(q0 * rq);
        lq[row * 32 + 16 + l16] = (bf16_t)(q1 * rq);
        lk[row * 32 + l16]      = (bf16_t)(k0 * rk);
        lk[row * 32 + 16 + l16] = (bf16_t)(k1 * rk);
        lvT[l16 * 64 + row]        = (bf16_t)(acc[mi][4][r] + bias_v0);
        lvT[(16 + l16) * 64 + row] = (bf16_t)(acc[mi][5][r] + bias_v1);
      }
    __syncthreads();

    // ---- Phase C: S = qn @ kn^T ----
    f32x4 s[4][4];
    {
      bf16x8 qa[4], kb[4];
#pragma unroll
      for (int mi = 0; mi < 4; ++mi) qa[mi] = *(const bf16x8*)&lq[(mi * 16 + l16) * 32 + ko];
#pragma unroll
      for (int ni = 0; ni < 4; ++ni) kb[ni] = *(const bf16x8*)&lk[(ni * 16 + l16) * 32 + ko];
#pragma unroll
      for (int mi = 0; mi < 4; ++mi)
#pragma unroll
        for (int ni = 0; ni < 4; ++ni) s[mi][ni] = mfma16(qa[mi], kb[ni], fzero);
    }

    const float scale = __expf(fminf(ldf(ls, h, F32), 4.6051702f));  // exp(min(ls, ln 100))

    // ---- scale + CPB bias + shifted-window mask ----
#pragma unroll
    for (int mi = 0; mi < 4; ++mi)
#pragma unroll
      for (int r = 0; r < 4; ++r) {
        int n   = mi * 16 + quad * 4 + r;  // query token
        int nrr = (wh == 7) ? (((n >> 3) < 4) ? 1 : 2) : 0;
        int ncc = (ww == 7) ? (((n & 7) < 4) ? 1 : 2) : 0;
        int regn = nrr * 3 + ncc;
#pragma unroll
        for (int ni = 0; ni < 4; ++ni) {
          int m   = ni * 16 + l16;         // key token
          int idx = ((n >> 3) - (m >> 3) + 7) * 15 + ((n & 7) - (m & 7) + 7);
          float v = s[mi][ni][r] * scale + btab[idx * 8 + h];
          if (regn != regm[ni]) v -= 100.f;
          s[mi][ni][r] = v;
        }
      }
    __syncthreads();

    // ---- Phase D: softmax rows, write P (overlays lq|lk as [64][64]) ----
    bf16_t* lp = lq;
#pragma unroll
    for (int mi = 0; mi < 4; ++mi)
#pragma unroll
      for (int r = 0; r < 4; ++r) {
        float mx = fmaxf(fmaxf(s[mi][0][r], s[mi][1][r]), fmaxf(s[mi][2][r], s[mi][3][r]));
        mx = fmaxf(mx, __shfl_xor(mx, 1)); mx = fmaxf(mx, __shfl_xor(mx, 2));
        mx = fmaxf(mx, __shfl_xor(mx, 4)); mx = fmaxf(mx, __shfl_xor(mx, 8));
        float sum = 0.f;
#pragma unroll
        for (int ni = 0; ni < 4; ++ni) {
          float p = __expf(s[mi][ni][r] - mx);
          s[mi][ni][r] = p;
          sum += p;
        }
        sum += __shfl_xor(sum, 1); sum += __shfl_xor(sum, 2);
        sum += __shfl_xor(sum, 4); sum += __shfl_xor(sum, 8);
        float inv = 1.f / sum;
        int row = mi * 16 + quad * 4 + r;
#pragma unroll
        for (int ni = 0; ni < 4; ++ni)
          lp[row * 64 + ni * 16 + l16] = (bf16_t)(s[mi][ni][r] * inv);
      }
    __syncthreads();

    // ---- Phase E: O = P @ V -> ybuf[token][h*32+d] ----
    f32x4 o[4][2];
#pragma unroll
    for (int mi = 0; mi < 4; ++mi) { o[mi][0] = fzero; o[mi][1] = fzero; }
#pragma unroll
    for (int k2 = 0; k2 < 2; ++k2) {
      int kof = k2 * 32 + ko;
      bf16x8 pa[4];
#pragma unroll
      for (int mi = 0; mi < 4; ++mi) pa[mi] = *(const bf16x8*)&lp[(mi * 16 + l16) * 64 + kof];
#pragma unroll
      for (int n2 = 0; n2 < 2; ++n2) {
        bf16x8 vb = *(const bf16x8*)&lvT[(n2 * 16 + l16) * 64 + kof];
#pragma unroll
        for (int mi = 0; mi < 4; ++mi) o[mi][n2] = mfma16(pa[mi], vb, o[mi][n2]);
      }
    }
#pragma unroll
    for (int mi = 0; mi < 4; ++mi)
#pragma unroll
      for (int r = 0; r < 4; ++r) {
        int row = mi * 16 + quad * 4 + r;
        ybuf[row * 256 + h * 32 + l16]      = (bf16_t)o[mi][0][r];
        ybuf[row * 256 + h * 32 + 16 + l16] = (bf16_t)o[mi][1][r];
      }
    __syncthreads();
  }

  // ---- Phase F: out = ybuf @ Wo^T + bo ----
  f32x4 acc2[4][4];
#pragma unroll
  for (int mi = 0; mi < 4; ++mi)
#pragma unroll
    for (int ni = 0; ni < 4; ++ni) acc2[mi][ni] = fzero;

#pragma unroll
  for (int kk = 0; kk < 8; ++kk) {
    bf16x8 af[4];
#pragma unroll
    for (int mi = 0; mi < 4; ++mi)
      af[mi] = *(const bf16x8*)&ybuf[(mi * 16 + l16) * 256 + kk * 32 + ko];
#pragma unroll
    for (int ni = 0; ni < 4; ++ni) {
      bf16x8 bfr = ld8(Wo, (wave * 64 + ni * 16 + l16) * 256 + kk * 32 + ko, F32);
#pragma unroll
      for (int mi = 0; mi < 4; ++mi) acc2[mi][ni] = mfma16(af[mi], bfr, acc2[mi][ni]);
    }
  }

  bf16_t* so = sm;  // 32 KB staging [token][feat]
  __syncthreads();
#pragma unroll
  for (int ni = 0; ni < 4; ++ni) {
    float bvv = ldf(bo, wave * 64 + ni * 16 + l16, F32);
#pragma unroll
    for (int mi = 0; mi < 4; ++mi)
#pragma unroll
      for (int r = 0; r < 4; ++r)
        so[(mi * 16 + quad * 4 + r) * 256 + wave * 64 + ni * 16 + l16] =
            (bf16_t)clampv(acc2[mi][ni][r] + bvv);
  }
  __syncthreads();

  // ---- unshift + window-reverse scatter ----
  const int ch = threadIdx.x & 31;  // 8-feat chunk within token row
  const int tr = threadIdx.x >> 5;
#pragma unroll
  for (int rr = 0; rr < 8; ++rr) {
    int row = rr * 8 + tr;
    int gh = (wh * 8 + (row >> 3) + 4) & 63;
    int gw = (ww * 8 + (row & 7) + 4) & 63;
    long gbase = ((long)(bb * 64 + gh) * 64 + gw) * 256 + ch * 8;
    if (F32) {
      const bf16_t* sp = &so[row * 256 + ch * 8];
      float4 v0, v1;
      v0.x = (float)sp[0]; v0.y = (float)sp[1]; v0.z = (float)sp[2]; v0.w = (float)sp[3];
      v1.x = (float)sp[4]; v1.y = (float)sp[5]; v1.z = (float)sp[6]; v1.w = (float)sp[7];
      float* op = (float*)outv + gbase;
      *(float4*)op = v0;
      *(float4*)(op + 4) = v1;
    } else {
      uint4 val = *(const uint4*)&so[row * 256 + ch * 8];
      *(uint4*)((bf16_t*)outv + gbase) = val;
    }
  }
}

extern "C" void kernel_launch(void* const* d_in, const int* in_sizes, int n_in,
                              void* d_out, int out_size, void* d_ws, size_t ws_size,
                              hipStream_t stream) {
  const void* x  = d_in[0];
  const void* Wq = d_in[1];
  const void* bq = d_in[2];
  const void* Wk = d_in[3];
  const void* bk = d_in[4];
  const void* Wv = d_in[5];
  const void* bv = d_in[6];
  const void* Wo = d_in[7];
  const void* bo = d_in[8];
  const void* ls = d_in[9];
  const void* w1 = d_in[10];
  const void* b1 = d_in[11];
  const void* w2 = d_in[12];

  float* tab = (float*)d_ws;            // 1800 floats
  int* flag  = (int*)d_ws + 1800;       // dtype flag

  hipLaunchKernelGGL(sniff_kernel, dim3(1), dim3(64), 0, stream,
                     (const unsigned int*)Wq, flag);
  hipLaunchKernelGGL(cpb_kernel, dim3(1), dim3(256), 0, stream, w1, b1, w2, tab, flag);
  hipLaunchKernelGGL((swin_fused<false>), dim3(2048), dim3(256), 0, stream,
                     x, Wq, bq, Wk, bk, Wv, bv, Wo, bo, ls, (const float*)tab, flag, d_out);
  hipLaunchKernelGGL((swin_fused<true>), dim3(2048), dim3(256), 0, stream,
                     x, Wq, bq, Wk, bk, Wv, bv, Wo, bo, ls, (const float*)tab, flag, d_out);
}

// Round 4
// 616.350 us; speedup vs baseline: 2.1814x; 2.1814x over previous
//
#include <hip/hip_runtime.h>

// Swin-V2 shifted-window attention, fp32 in/out (settled R3), MI355X gfx950.
// R4: kill uncoalesced MFMA-fragment gathers.
//  - cpb_kernel parallelized (225 blocks x 1 wave) — was ~500us single-block.
//  - x-window staged once/block into LDS, fragment-major bf16 -> conflict-free ds_read_b128.
//  - weights pre-converted to fragment-major bf16 in d_ws (prep_w) -> lane-contiguous
//    1KB/instr loads from L2. Fallback template if ws_size too small.
//  - all LDS tiles fragment-major; per-wave phases barrier-free; y overlays dead x-tile.
// MFMA 16x16x32 bf16 layouts (HW-verified): A[m=lane&15][k=(lane>>4)*8+j],
// C/D[col=lane&15][row=(lane>>4)*4+reg]; B mirrors A.
// Fragment-major storage of a [T x F] operand tile: addr(t,f) = ((f>>3)*64 + t)*8 + (f&7).

typedef __bf16 bf16_t;
typedef __attribute__((ext_vector_type(8))) __bf16 bf16x8;
typedef __attribute__((ext_vector_type(4))) float f32x4;

__device__ __forceinline__ f32x4 mfma16(bf16x8 a, bf16x8 b, f32x4 c) {
  return __builtin_amdgcn_mfma_f32_16x16x32_bf16(a, b, c, 0, 0, 0);
}

__device__ __forceinline__ bf16x8 cvt8(const float* f) {
  float4 a = *(const float4*)f;
  float4 b = *(const float4*)(f + 4);
  bf16x8 r;
  r[0] = (bf16_t)a.x; r[1] = (bf16_t)a.y; r[2] = (bf16_t)a.z; r[3] = (bf16_t)a.w;
  r[4] = (bf16_t)b.x; r[5] = (bf16_t)b.y; r[6] = (bf16_t)b.z; r[7] = (bf16_t)b.w;
  return r;
}

__device__ __forceinline__ float clampv(float v) {
  return fminf(fmaxf(v, -1.0e4f), 1.0e4f);
}

// ---------------- CPB-MLP bias table -> d_ws (parallel: 225 blocks x 64 thr) ----------
__global__ void cpb_kernel(const float* __restrict__ w1, const float* __restrict__ b1,
                           const float* __restrict__ w2, float* __restrict__ tab) {
  int e = blockIdx.x;      // 0..224
  int t = threadIdx.x;     // 0..63
  int a = e / 15, bcol = e % 15;
  float t0 = ((float)(a - 7) / 7.0f) * 8.0f;
  float t1 = ((float)(bcol - 7) / 7.0f) * 8.0f;
  float s0 = (t0 > 0.f) ? 1.f : ((t0 < 0.f) ? -1.f : 0.f);
  float s1 = (t1 > 0.f) ? 1.f : ((t1 < 0.f) ? -1.f : 0.f);
  t0 = s0 * log2f(fabsf(t0) + 1.f) * (1.0f / 3.0f);  // /log2(8)
  t1 = s1 * log2f(fabsf(t1) + 1.f) * (1.0f / 3.0f);
  float accv[8];
#pragma unroll
  for (int i = 0; i < 8; ++i) accv[i] = 0.f;
#pragma unroll
  for (int i = 0; i < 8; ++i) {
    int j = t + 64 * i;
    float hd = fmaxf(t0 * w1[2 * j] + t1 * w1[2 * j + 1] + b1[j], 0.f);
#pragma unroll
    for (int hh = 0; hh < 8; ++hh) accv[hh] += hd * w2[hh * 512 + j];
  }
#pragma unroll
  for (int hh = 0; hh < 8; ++hh) {
    float v = accv[hh];
    v += __shfl_xor(v, 1);  v += __shfl_xor(v, 2);  v += __shfl_xor(v, 4);
    v += __shfl_xor(v, 8);  v += __shfl_xor(v, 16); v += __shfl_xor(v, 32);
    accv[hh] = v;
  }
  if (t < 8) tab[e * 8 + t] = 16.f / (1.f + __expf(-accv[t]));
}

// -------- prep_w: weights -> fragment-major bf16 in d_ws ----------------------------
// ws layout: wf[(mat*16 + rblk)*8 + kk][lane][8] ; mat 0..3 = Wq,Wk,Wv,Wo; rblk = row>>4.
// Reader frag (rows rblk*16+l16, cols kk*32+quad*8+j) = wf + (((mat*16+rblk)*8+kk)*64+lane)*8.
__global__ void prep_w(const float* __restrict__ Wq, const float* __restrict__ Wk,
                       const float* __restrict__ Wv, const float* __restrict__ Wo,
                       bf16_t* __restrict__ wf) {
  int gid = blockIdx.x * 256 + threadIdx.x;  // 32768 frags of 8 elements
  const float* Ws[4] = {Wq, Wk, Wv, Wo};
  int mat = gid >> 13, rem = gid & 8191;
  int rblk = rem >> 9, kk = (rem >> 6) & 7, lane = rem & 63;
  int row = rblk * 16 + (lane & 15);
  int col = kk * 32 + (lane >> 4) * 8;
  bf16x8 v = cvt8(Ws[mat] + row * 256 + col);
  *(bf16x8*)(wf + (size_t)gid * 8) = v;
}

// ---------------- fused per-window attention ---------------------------------------
template <bool PREP>
__global__ void __launch_bounds__(256, 2) swin_fused(
    const float* __restrict__ x,
    const float* __restrict__ Wq, const float* __restrict__ bq,
    const float* __restrict__ Wk, const float* __restrict__ bk,
    const float* __restrict__ Wv, const float* __restrict__ bv,
    const float* __restrict__ Wo, const float* __restrict__ bo,
    const float* __restrict__ ls, const float* __restrict__ btab,
    const bf16_t* __restrict__ wf, float* __restrict__ out) {
  __shared__ __align__(16) bf16_t xsf[16384];      // 32 KB: x frags; later y frags
  __shared__ __align__(16) bf16_t scr[4 * 6144];   // 48 KB: per-wave q|k|vT (P overlays q|k)
  const int tid = threadIdx.x;
  const int lane = tid & 63, wave = tid >> 6, quad = lane >> 4, l16 = lane & 15;
  const int win = blockIdx.x, bb = win >> 6, wh = (win >> 3) & 7, ww = win & 7;
  const f32x4 fz = {0.f, 0.f, 0.f, 0.f};

  // ---- Phase 0: stage shifted x-window -> xsf (fragment-major bf16), coalesced ----
  {
    int t = tid >> 2, fq = tid & 3;
    int gh = (wh * 8 + (t >> 3) + 4) & 63;
    int gw = (ww * 8 + (t & 7) + 4) & 63;
    const float* xp = x + (size_t)((bb * 64 + gh) * 64 + gw) * 256 + fq * 64;
    bf16_t* dst = xsf + t * 8;
#pragma unroll
    for (int fc = 0; fc < 8; ++fc)
      *(bf16x8*)(dst + (fq * 8 + fc) * 512) = cvt8(xp + fc * 8);
  }
  __syncthreads();

  bf16_t* qf = scr + wave * 6144;  // q frags   [2048 el]
  bf16_t* kf = qf + 2048;          // k frags   [2048 el]
  bf16_t* vf = qf + 4096;          // vT frags  [2048 el]
  bf16_t* pf = qf;                 // P frags   [4096 el] overlay q|k (dead after QK^T)

  // key-region ids for shifted-window mask
  int regm[4];
#pragma unroll
  for (int ni = 0; ni < 4; ++ni) {
    int m = ni * 16 + l16;
    int rr = (wh == 7) ? (((m >> 3) < 4) ? 1 : 2) : 0;
    int cc = (ww == 7) ? (((m & 7) < 4) ? 1 : 2) : 0;
    regm[ni] = rr * 3 + cc;
  }

  f32x4 oh[2][4][2];  // attention outputs for both head passes (C-layout)

  for (int hp = 0; hp < 2; ++hp) {
    const int h = hp * 4 + wave;

    // ---- Phase A: QKV projection (A: LDS frags; B: frag-major global weights) ----
    f32x4 acc[4][6];
#pragma unroll
    for (int mi = 0; mi < 4; ++mi)
#pragma unroll
      for (int ni = 0; ni < 6; ++ni) acc[mi][ni] = fz;

#pragma unroll
    for (int kk = 0; kk < 8; ++kk) {
      bf16x8 af[4];
      const bf16_t* xb = xsf + ((kk * 4 + quad) * 64 + l16) * 8;
#pragma unroll
      for (int mi = 0; mi < 4; ++mi) af[mi] = *(const bf16x8*)(xb + mi * 128);
      bf16x8 bw[6];
      if (PREP) {
#pragma unroll
        for (int m3 = 0; m3 < 3; ++m3)
#pragma unroll
          for (int ni = 0; ni < 2; ++ni)
            bw[m3 * 2 + ni] = *(const bf16x8*)(
                wf + (size_t)(((m3 * 16 + h * 2 + ni) * 8 + kk) * 64 + lane) * 8);
      } else {
        const float* Wm[3] = {Wq, Wk, Wv};
#pragma unroll
        for (int m3 = 0; m3 < 3; ++m3)
#pragma unroll
          for (int ni = 0; ni < 2; ++ni)
            bw[m3 * 2 + ni] =
                cvt8(Wm[m3] + (h * 32 + ni * 16 + l16) * 256 + kk * 32 + quad * 8);
      }
#pragma unroll
      for (int ni = 0; ni < 6; ++ni)
#pragma unroll
        for (int mi = 0; mi < 4; ++mi) acc[mi][ni] = mfma16(af[mi], bw[ni], acc[mi][ni]);
    }

    // hp1: all waves are past their last xsf read once everyone reaches here.
    if (hp == 1) {
      __syncthreads();
      // write hp0's O into y frags (overlay xsf): f = wave*32 + d
#pragma unroll
      for (int mi = 0; mi < 4; ++mi)
#pragma unroll
        for (int r = 0; r < 4; ++r) {
          int row = mi * 16 + quad * 4 + r;
          xsf[(wave * 4 + (l16 >> 3)) * 512 + row * 8 + (l16 & 7)]     = (bf16_t)oh[0][mi][0][r];
          xsf[(wave * 4 + 2 + (l16 >> 3)) * 512 + row * 8 + (l16 & 7)] = (bf16_t)oh[0][mi][1][r];
        }
    }

    const float bq0 = bq[h * 32 + l16],      bq1 = bq[h * 32 + 16 + l16];
    const float bk0 = bk[h * 32 + l16],      bk1 = bk[h * 32 + 16 + l16];
    const float bv0 = bv[h * 32 + l16],      bv1 = bv[h * 32 + 16 + l16];

    // ---- Phase B: bias + cosine-normalize; stage q,k,vT frags (wave-private) ----
#pragma unroll
    for (int mi = 0; mi < 4; ++mi)
#pragma unroll
      for (int r = 0; r < 4; ++r) {
        float q0 = acc[mi][0][r] + bq0, q1 = acc[mi][1][r] + bq1;
        float k0 = acc[mi][2][r] + bk0, k1 = acc[mi][3][r] + bk1;
        float sq = q0 * q0 + q1 * q1;
        sq += __shfl_xor(sq, 1); sq += __shfl_xor(sq, 2);
        sq += __shfl_xor(sq, 4); sq += __shfl_xor(sq, 8);
        float rq = 1.f / fmaxf(sqrtf(sq), 1e-12f);
        float sk = k0 * k0 + k1 * k1;
        sk += __shfl_xor(sk, 1); sk += __shfl_xor(sk, 2);
        sk += __shfl_xor(sk, 4); sk += __shfl_xor(sk, 8);
        float rk = 1.f / fmaxf(sqrtf(sk), 1e-12f);
        int row = mi * 16 + quad * 4 + r;
        int qa0 = (l16 >> 3) * 512 + row * 8 + (l16 & 7);
        qf[qa0]              = (bf16_t)(q0 * rq);
        qf[qa0 + 2 * 512]    = (bf16_t)(q1 * rq);
        kf[qa0]              = (bf16_t)(k0 * rk);
        kf[qa0 + 2 * 512]    = (bf16_t)(k1 * rk);
        // vT frag element (d,t): addr = ((d>>4)*2 + (t>>5))*512 + (((t>>3)&3)*16 + (d&15))*8 + (t&7)
        int vb = (((row >> 3) & 3) * 16 + l16) * 8 + (row & 7);
        vf[(row >> 5) * 512 + vb]       = (bf16_t)(acc[mi][4][r] + bv0);
        vf[(2 + (row >> 5)) * 512 + vb] = (bf16_t)(acc[mi][5][r] + bv1);
      }

    // ---- Phase C: S = qn @ kn^T (conflict-free b128 frag reads) ----
    f32x4 s[4][4];
    {
      bf16x8 qa[4], kb[4];
#pragma unroll
      for (int mi = 0; mi < 4; ++mi)
        qa[mi] = *(const bf16x8*)(qf + (quad * 64 + mi * 16 + l16) * 8);
#pragma unroll
      for (int ni = 0; ni < 4; ++ni)
        kb[ni] = *(const bf16x8*)(kf + (quad * 64 + ni * 16 + l16) * 8);
#pragma unroll
      for (int mi = 0; mi < 4; ++mi)
#pragma unroll
        for (int ni = 0; ni < 4; ++ni) s[mi][ni] = mfma16(qa[mi], kb[ni], fz);
    }

    const float scale = __expf(fminf(ls[h], 4.6051702f));  // exp(min(ls, ln 100))

    // ---- scale + CPB bias + shifted-window mask ----
#pragma unroll
    for (int mi = 0; mi < 4; ++mi)
#pragma unroll
      for (int r = 0; r < 4; ++r) {
        int n = mi * 16 + quad * 4 + r;  // query token
        int nrr = (wh == 7) ? (((n >> 3) < 4) ? 1 : 2) : 0;
        int ncc = (ww == 7) ? (((n & 7) < 4) ? 1 : 2) : 0;
        int regn = nrr * 3 + ncc;
#pragma unroll
        for (int ni = 0; ni < 4; ++ni) {
          int m = ni * 16 + l16;  // key token
          int idx = ((n >> 3) - (m >> 3) + 7) * 15 + ((n & 7) - (m & 7) + 7);
          float v = s[mi][ni][r] * scale + btab[idx * 8 + h];
          if (regn != regm[ni]) v -= 100.f;
          s[mi][ni][r] = v;
        }
      }

    // ---- Phase D: softmax rows -> P frags (overlay q|k, wave-private) ----
#pragma unroll
    for (int mi = 0; mi < 4; ++mi)
#pragma unroll
      for (int r = 0; r < 4; ++r) {
        float mx = fmaxf(fmaxf(s[mi][0][r], s[mi][1][r]), fmaxf(s[mi][2][r], s[mi][3][r]));
        mx = fmaxf(mx, __shfl_xor(mx, 1)); mx = fmaxf(mx, __shfl_xor(mx, 2));
        mx = fmaxf(mx, __shfl_xor(mx, 4)); mx = fmaxf(mx, __shfl_xor(mx, 8));
        float sum = 0.f;
#pragma unroll
        for (int ni = 0; ni < 4; ++ni) {
          float p = __expf(s[mi][ni][r] - mx);
          s[mi][ni][r] = p;
          sum += p;
        }
        sum += __shfl_xor(sum, 1); sum += __shfl_xor(sum, 2);
        sum += __shfl_xor(sum, 4); sum += __shfl_xor(sum, 8);
        float inv = 1.f / sum;
        int row = mi * 16 + quad * 4 + r;
#pragma unroll
        for (int ni = 0; ni < 4; ++ni) {
          int m = ni * 16 + l16;  // key token
          int pa = ((row >> 4) * 2 + (m >> 5)) * 512 +
                   (((m >> 3) & 3) * 16 + (row & 15)) * 8 + (m & 7);
          pf[pa] = (bf16_t)(s[mi][ni][r] * inv);
        }
      }

    // ---- Phase E: O = P @ V (conflict-free b128 frag reads) ----
#pragma unroll
    for (int mi = 0; mi < 4; ++mi) { oh[hp][mi][0] = fz; oh[hp][mi][1] = fz; }
#pragma unroll
    for (int k2 = 0; k2 < 2; ++k2) {
      bf16x8 pa[4];
#pragma unroll
      for (int mi = 0; mi < 4; ++mi)
        pa[mi] = *(const bf16x8*)(pf + ((mi * 2 + k2) * 64 + lane) * 8);
#pragma unroll
      for (int n2 = 0; n2 < 2; ++n2) {
        bf16x8 vb = *(const bf16x8*)(vf + ((n2 * 2 + k2) * 64 + lane) * 8);
#pragma unroll
        for (int mi = 0; mi < 4; ++mi) oh[hp][mi][n2] = mfma16(pa[mi], vb, oh[hp][mi][n2]);
      }
    }
  }

  // write hp1's O into y frags: f = (4+wave)*32 + d
#pragma unroll
  for (int mi = 0; mi < 4; ++mi)
#pragma unroll
    for (int r = 0; r < 4; ++r) {
      int row = mi * 16 + quad * 4 + r;
      int h1 = 4 + wave;
      xsf[(h1 * 4 + (l16 >> 3)) * 512 + row * 8 + (l16 & 7)]     = (bf16_t)oh[1][mi][0][r];
      xsf[(h1 * 4 + 2 + (l16 >> 3)) * 512 + row * 8 + (l16 & 7)] = (bf16_t)oh[1][mi][1][r];
    }
  __syncthreads();

  // ---- Phase F: out = y @ Wo^T + bo, direct unshift-scatter store ----
  f32x4 a2[4][4];
#pragma unroll
  for (int mi = 0; mi < 4; ++mi)
#pragma unroll
    for (int ni = 0; ni < 4; ++ni) a2[mi][ni] = fz;

#pragma unroll
  for (int kk = 0; kk < 8; ++kk) {
    bf16x8 af[4];
    const bf16_t* yb = xsf + ((kk * 4 + quad) * 64 + l16) * 8;
#pragma unroll
    for (int mi = 0; mi < 4; ++mi) af[mi] = *(const bf16x8*)(yb + mi * 128);
#pragma unroll
    for (int ni = 0; ni < 4; ++ni) {
      bf16x8 bw;
      if (PREP)
        bw = *(const bf16x8*)(wf + (size_t)(((48 + wave * 4 + ni) * 8 + kk) * 64 + lane) * 8);
      else
        bw = cvt8(Wo + (wave * 64 + ni * 16 + l16) * 256 + kk * 32 + quad * 8);
#pragma unroll
      for (int mi = 0; mi < 4; ++mi) a2[mi][ni] = mfma16(af[mi], bw, a2[mi][ni]);
    }
  }

  float bor[4];
#pragma unroll
  for (int ni = 0; ni < 4; ++ni) bor[ni] = bo[wave * 64 + ni * 16 + l16];
#pragma unroll
  for (int mi = 0; mi < 4; ++mi)
#pragma unroll
    for (int r = 0; r < 4; ++r) {
      int row = mi * 16 + quad * 4 + r;
      int gh = (wh * 8 + (row >> 3) + 4) & 63;
      int gw = (ww * 8 + (row & 7) + 4) & 63;
      float* op = out + (size_t)((bb * 64 + gh) * 64 + gw) * 256 + wave * 64 + l16;
#pragma unroll
      for (int ni = 0; ni < 4; ++ni) op[ni * 16] = clampv(a2[mi][ni][r] + bor[ni]);
    }
}

extern "C" void kernel_launch(void* const* d_in, const int* in_sizes, int n_in,
                              void* d_out, int out_size, void* d_ws, size_t ws_size,
                              hipStream_t stream) {
  const float* x  = (const float*)d_in[0];
  const float* Wq = (const float*)d_in[1];
  const float* bq = (const float*)d_in[2];
  const float* Wk = (const float*)d_in[3];
  const float* bk = (const float*)d_in[4];
  const float* Wv = (const float*)d_in[5];
  const float* bv = (const float*)d_in[6];
  const float* Wo = (const float*)d_in[7];
  const float* bo = (const float*)d_in[8];
  const float* ls = (const float*)d_in[9];
  const float* w1 = (const float*)d_in[10];
  const float* b1 = (const float*)d_in[11];
  const float* w2 = (const float*)d_in[12];

  float* tab = (float*)d_ws;                           // 1800 floats (7.2 KB)
  bf16_t* wfrag = (bf16_t*)((char*)d_ws + 7680);       // 512 KB fragment-major weights
  const bool prep = ws_size >= (size_t)(7680 + 524288);  // constant across calls

  hipLaunchKernelGGL(cpb_kernel, dim3(225), dim3(64), 0, stream, w1, b1, w2, tab);
  if (prep) {
    hipLaunchKernelGGL(prep_w, dim3(128), dim3(256), 0, stream, Wq, Wk, Wv, Wo, wfrag);
    hipLaunchKernelGGL((swin_fused<true>), dim3(2048), dim3(256), 0, stream,
                       x, Wq, bq, Wk, bk, Wv, bv, Wo, bo, ls, tab, wfrag, (float*)d_out);
  } else {
    hipLaunchKernelGGL((swin_fused<false>), dim3(2048), dim3(256), 0, stream,
                       x, Wq, bq, Wk, bk, Wv, bv, Wo, bo, ls, tab, wfrag, (float*)d_out);
  }
}